// Round 6
// baseline (611.750 us; speedup 1.0000x reference)
//
#include <hip/hip_runtime.h>

typedef _Float16 f16x8 __attribute__((ext_vector_type(8)));
typedef _Float16 f16x4 __attribute__((ext_vector_type(4)));
typedef float f32x4 __attribute__((ext_vector_type(4)));
typedef unsigned short u16x8 __attribute__((ext_vector_type(8)));
typedef unsigned int u32;

#define MFMA16H(a, b, c) __builtin_amdgcn_mfma_f32_16x16x32_f16(a, b, c, 0, 0, 0)

#if __has_builtin(__builtin_amdgcn_exp2f)
#define EXP2F(x) __builtin_amdgcn_exp2f(x)
#else
#define EXP2F(x) exp2f(x)
#endif

#define LOG2E 1.44269504088896340736f
#define SHIFT2 5.0f   // log2-shift: p' = 2^(l*log2e-5) in [2^-22, 2^12] -> fp16-safe

__device__ __forceinline__ unsigned short f2bf(float x) {
  unsigned u = __float_as_uint(x);
  u += 0x7FFF + ((u >> 16) & 1);   // round-to-nearest-even
  return (unsigned short)(u >> 16);
}
__device__ __forceinline__ float bf2f(unsigned short h) {
  return __uint_as_float(((unsigned)h) << 16);
}
__device__ __forceinline__ f16x8 ldh8(const _Float16* p) {
  return *reinterpret_cast<const f16x8*>(p);
}
__device__ __forceinline__ u16x8 ldu8(const unsigned short* p) {
  return *reinterpret_cast<const u16x8*>(p);
}
__device__ __forceinline__ f16x8 cvt8(float4 a, float4 b) {
  f16x8 r;
  r[0] = (_Float16)a.x; r[1] = (_Float16)a.y; r[2] = (_Float16)a.z; r[3] = (_Float16)a.w;
  r[4] = (_Float16)b.x; r[5] = (_Float16)b.y; r[6] = (_Float16)b.z; r[7] = (_Float16)b.w;
  return r;
}

// ---------------- mask -> permuted bf16( mask * -1e9 * log2e ) ----------------
__global__ __launch_bounds__(256) void prep_mask_perm(const float* __restrict__ src,
                                                      unsigned short* __restrict__ dst) {
  const int blk = blockIdx.x;               // (b*32+qt)*32 + kt
  const int kt = blk & 31, bq = blk >> 5;
  const int b = bq >> 5, qt = bq & 31;
  const int lane = threadIdx.x;
  const int w = lane >> 6, lg = (lane >> 4) & 3, lr = lane & 15;
  const int q0 = qt * 64;
  const float cs = -1e9f * LOG2E;
  unsigned short vals[16];
#pragma unroll
  for (int c = 0; c < 4; ++c)
#pragma unroll
    for (int r = 0; r < 4; ++r) {
      const int qr = q0 + w * 16 + lg * 4 + r;
      const int kc = kt * 64 + c * 16 + lr;
      vals[c * 4 + r] = f2bf(src[((size_t)b * 2048 + qr) * 2048 + kc] * cs);
    }
  uint4* out = reinterpret_cast<uint4*>(dst) + ((size_t)blk * 256 + lane) * 2;
  out[0] = *reinterpret_cast<uint4*>(&vals[0]);
  out[1] = *reinterpret_cast<uint4*>(&vals[8]);
}

// ---------------- fused projection GEMM (Q,K,V), fp32 inputs, fp16 out ----------------
__global__ __launch_bounds__(256, 3) void proj_gemm_kernel(
    const float* __restrict__ qin, const float* __restrict__ kin, const float* __restrict__ vin,
    const float* __restrict__ wq, const float* __restrict__ wk, const float* __restrict__ wv,
    const float* __restrict__ bq, const float* __restrict__ bk, const float* __restrict__ bv,
    _Float16* __restrict__ qhf, _Float16* __restrict__ khf, _Float16* __restrict__ vhT) {
  __shared__ __align__(16) _Float16 As[128 * 32];
  __shared__ __align__(16) _Float16 Bs[128 * 32];

  const int mode = blockIdx.x >> 8;
  const int t = blockIdx.x & 255;
  const float* A = mode == 0 ? qin : (mode == 1 ? kin : vin);
  const float* B = mode == 0 ? wq : (mode == 1 ? wk : wv);
  const float* bias = mode == 0 ? bq : (mode == 1 ? bk : bv);
  _Float16* outp = mode == 0 ? qhf : (mode == 1 ? khf : vhT);

  const int tid = threadIdx.x;
  const int tm = t & 31, tn = t >> 5;
  const int m0 = tm * 128, n0 = tn * 128;
  const int w = tid >> 6, l = tid & 63, lg = l >> 4, lr = l & 15;
  const int wr = w >> 1, wc = w & 1;
  const int srow = tid >> 2, scol = (tid & 3) * 8;

  f32x4 acc[4][4] = {};

  for (int kt = 0; kt < 32; ++kt) {
    const int k0 = kt * 32;
    float4 ra[2][2], rb[2][2];
#pragma unroll
    for (int it = 0; it < 2; ++it) {
      const int row = it * 64 + srow;
      const float* pa = A + (size_t)(m0 + row) * 1024 + k0 + scol;
      const float* pb = B + (size_t)(n0 + row) * 1024 + k0 + scol;
      ra[it][0] = *reinterpret_cast<const float4*>(pa);
      ra[it][1] = *reinterpret_cast<const float4*>(pa + 4);
      rb[it][0] = *reinterpret_cast<const float4*>(pb);
      rb[it][1] = *reinterpret_cast<const float4*>(pb + 4);
    }
    __syncthreads();
#pragma unroll
    for (int it = 0; it < 2; ++it) {
      const int eo = (it * 256 + tid) * 8;
      *reinterpret_cast<f16x8*>(As + eo) = cvt8(ra[it][0], ra[it][1]);
      *reinterpret_cast<f16x8*>(Bs + eo) = cvt8(rb[it][0], rb[it][1]);
    }
    __syncthreads();

    f16x8 fa[4], fb[4];
#pragma unroll
    for (int i = 0; i < 4; ++i) {
      fa[i] = ldh8(As + (wr * 64 + i * 16 + lr) * 32 + lg * 8);
      fb[i] = ldh8(Bs + (wc * 64 + i * 16 + lr) * 32 + lg * 8);
    }
#pragma unroll
    for (int i = 0; i < 4; ++i)
#pragma unroll
      for (int j = 0; j < 4; ++j)
        acc[i][j] = MFMA16H(fa[i], fb[j], acc[i][j]);
  }

#pragma unroll
  for (int i = 0; i < 4; ++i) {
    const int mrow = m0 + wr * 64 + i * 16 + lg * 4;
#pragma unroll
    for (int j = 0; j < 4; ++j) {
      const int ncol = n0 + wc * 64 + j * 16 + lr;
      const float bv = bias[ncol];
#pragma unroll
      for (int r = 0; r < 4; ++r) {
        const int m = mrow + r;
        const float v = acc[i][j][r] + bv;
        const int bb = m >> 11, s = m & 2047, hh = ncol >> 6, d = ncol & 63;
        if (mode != 2)
          outp[((size_t)(bb * 16 + hh) * 2048 + s) * 64 + d] = (_Float16)v;
        else
          outp[((size_t)(bb * 16 + hh) * 64 + d) * 2048 + s] = (_Float16)v;
      }
    }
  }
}

// ---------------- dense GEMM: fp16 A (o_h), fp32 B (dense_w), fp32 out ----------------
__global__ __launch_bounds__(256) void dense_gemm_kernel(
    const _Float16* __restrict__ A, const float* __restrict__ B,
    const float* __restrict__ bias, float* __restrict__ out_f) {
  __shared__ __align__(16) _Float16 As[128 * 32];
  __shared__ __align__(16) _Float16 Bs[128 * 32];

  const int tid = threadIdx.x;
  const int tm = blockIdx.x & 31, tn = blockIdx.x >> 5;
  const int m0 = tm * 128, n0 = tn * 128;
  const int w = tid >> 6, l = tid & 63, lg = l >> 4, lr = l & 15;
  const int wr = w >> 1, wc = w & 1;
  const int srow = tid >> 2, scol = (tid & 3) * 8;

  f32x4 acc[4][4] = {};

  for (int kt = 0; kt < 32; ++kt) {
    const int k0 = kt * 32;
    uint4 ra[2];
    float4 rb[2][2];
#pragma unroll
    for (int it = 0; it < 2; ++it) {
      const int row = it * 64 + srow;
      ra[it] = *reinterpret_cast<const uint4*>(A + (size_t)(m0 + row) * 1024 + k0 + scol);
      const float* pb = B + (size_t)(n0 + row) * 1024 + k0 + scol;
      rb[it][0] = *reinterpret_cast<const float4*>(pb);
      rb[it][1] = *reinterpret_cast<const float4*>(pb + 4);
    }
    __syncthreads();
#pragma unroll
    for (int it = 0; it < 2; ++it) {
      const int eo = (it * 256 + tid) * 8;
      *reinterpret_cast<uint4*>(As + eo) = ra[it];
      *reinterpret_cast<f16x8*>(Bs + eo) = cvt8(rb[it][0], rb[it][1]);
    }
    __syncthreads();

    f16x8 fa[4], fb[4];
#pragma unroll
    for (int i = 0; i < 4; ++i) {
      fa[i] = ldh8(As + (wr * 64 + i * 16 + lr) * 32 + lg * 8);
      fb[i] = ldh8(Bs + (wc * 64 + i * 16 + lr) * 32 + lg * 8);
    }
#pragma unroll
    for (int i = 0; i < 4; ++i)
#pragma unroll
      for (int j = 0; j < 4; ++j)
        acc[i][j] = MFMA16H(fa[i], fb[j], acc[i][j]);
  }

#pragma unroll
  for (int i = 0; i < 4; ++i) {
    const int mrow = m0 + wr * 64 + i * 16 + lg * 4;
#pragma unroll
    for (int j = 0; j < 4; ++j) {
      const int ncol = n0 + wc * 64 + j * 16 + lr;
      const float bv = bias[ncol];
#pragma unroll
      for (int r = 0; r < 4; ++r)
        out_f[(size_t)(mrow + r) * 1024 + ncol] = acc[i][j][r] + bv;
    }
  }
}

// ---------------- attention: QK^T + exp + p'-store (fp16) + row sums + PV ----------------
// Single pass. p' = 2^(l*log2e - SHIFT2) stored unnormalized as fp16; fixup
// kernel multiplies by scal = 1/sum. Explicit 1-deep K/mask register pipeline;
// no barriers in the kt loop (p_lds rows are wave-local).
__global__ __launch_bounds__(256, 2) void attn_pv_kernel(
    const _Float16* __restrict__ qh, const _Float16* __restrict__ kh,
    const _Float16* __restrict__ vT,
    const float* __restrict__ rel_bias, const unsigned short* __restrict__ mperm,
    _Float16* __restrict__ o_h, _Float16* __restrict__ p16,
    float* __restrict__ scal) {
  __shared__ float rb2[2112];
  __shared__ __align__(16) _Float16 p_lds[64 * 76];

  const int bid = blockIdx.x;
  const int wg = ((bid & 7) << 7) | (bid >> 3);   // XCD-chunked: 4 bh per XCD
  const int bh = wg >> 5, qt = wg & 31;
  const int b = bh >> 4, h = bh & 15;
  const int q0 = qt * 64;
  const int tid = threadIdx.x;
  const int w = tid >> 6, l = tid & 63, lg = l >> 4, lr = l & 15;

  for (int t = tid; t < 2111; t += 256)
    rb2[t] = rel_bias[(q0 + t) * 16 + h] * LOG2E - SHIFT2;

  const size_t bh_off = (size_t)bh * 2048 * 64;
  const _Float16* qhb = qh + bh_off;
  const _Float16* khb = kh + bh_off;
  const _Float16* vTb = vT + bh_off;
  const unsigned short* mpb =
      mperm + (((size_t)(b * 32 + qt) * 32) * 256 + tid) * 16;
  _Float16* pbh = p16 + (size_t)bh * 2048 * 2048;

  f16x8 qf[2];
  {
    const size_t qrow = (size_t)(q0 + w * 16 + lr) * 64;
    qf[0] = ldh8(qhb + qrow + lg * 8);
    qf[1] = ldh8(qhb + qrow + 32 + lg * 8);
  }
  __syncthreads();  // rb2 ready (only barrier in the kernel)

  const int qbase = w * 16 + lg * 4;
  const float c1 = 0.125f * LOG2E;
  float sacc[4] = {0.f, 0.f, 0.f, 0.f};
  f32x4 acc_o[4] = {};

  f16x8 kA[8], kB[8];
  u16x8 mA[2], mB[2];

  auto loadK = [&](int kt, f16x8* kd, u16x8* md) {
    md[0] = ldu8(mpb + (size_t)kt * 4096);
    md[1] = ldu8(mpb + (size_t)kt * 4096 + 8);
#pragma unroll
    for (int c = 0; c < 4; ++c) {
      const _Float16* kr = khb + (size_t)(kt * 64 + c * 16 + lr) * 64 + lg * 8;
      kd[c * 2] = ldh8(kr);
      kd[c * 2 + 1] = ldh8(kr + 32);
    }
  };

  auto step = [&](int kt, const f16x8* kd, const u16x8* md) {
#pragma unroll
    for (int c = 0; c < 4; ++c) {
      f32x4 acc = {};
      acc = MFMA16H(qf[0], kd[c * 2], acc);
      acc = MFMA16H(qf[1], kd[c * 2 + 1], acc);
      const int kc = kt * 64 + c * 16 + lr;
#pragma unroll
      for (int r = 0; r < 4; ++r) {
        const float mbf = bf2f((unsigned short)md[c >> 1][(c & 1) * 4 + r]);
        const float l2 = fmaf(acc[r], c1, rb2[qbase + r - kc + 2047]) + mbf;
        const float p = EXP2F(l2);
        sacc[r] += p;
        p_lds[(qbase + r) * 76 + c * 16 + lr] = (_Float16)p;
      }
    }
    // p rows are wave-local: same-wave lgkmcnt ordering only, no barrier
    f16x8 pf0 = ldh8(p_lds + (w * 16 + lr) * 76 + lg * 8);
    f16x8 pf1 = ldh8(p_lds + (w * 16 + lr) * 76 + 32 + lg * 8);
    // store unnormalized p' (fp16): lanes cover 64B row-chunks
    _Float16* prow = pbh + (size_t)(q0 + w * 16 + lr) * 2048 + kt * 64 + lg * 8;
    *reinterpret_cast<f16x8*>(prow) = pf0;
    *reinterpret_cast<f16x8*>(prow + 32) = pf1;
#pragma unroll
    for (int n = 0; n < 4; ++n) {
      const _Float16* vr = vTb + (size_t)(n * 16 + lr) * 2048 + kt * 64 + lg * 8;
      acc_o[n] = MFMA16H(pf0, ldh8(vr), acc_o[n]);
      acc_o[n] = MFMA16H(pf1, ldh8(vr + 32), acc_o[n]);
    }
  };

  loadK(0, kA, mA);
  for (int kt = 0; kt < 32; kt += 2) {
    loadK(kt + 1, kB, mB);          // issue kt+1 loads before kt's compute
    step(kt, kA, mA);
    loadK((kt + 2) & 31, kA, mA);   // kt=30 -> wraps to 0 (harmless)
    step(kt + 1, kB, mB);
  }

  float inv_s[4];
#pragma unroll
  for (int r = 0; r < 4; ++r) {
    float s = sacc[r];
    s += __shfl_xor(s, 1);
    s += __shfl_xor(s, 2);
    s += __shfl_xor(s, 4);
    s += __shfl_xor(s, 8);
    inv_s[r] = 1.0f / s;
    if (lr == 0) scal[(size_t)bh * 2048 + q0 + qbase + r] = inv_s[r];
  }

#pragma unroll
  for (int n = 0; n < 4; ++n)
#pragma unroll
    for (int r = 0; r < 4; ++r) {
      const int qr = q0 + qbase + r;
      const int d = n * 16 + lr;
      o_h[((size_t)(b * 2048 + qr) * 16 + h) * 64 + d] = (_Float16)(acc_o[n][r] * inv_s[r]);
    }
}

// ---------------- normalization fixup: attn = fp16(p') * scal[row] ----------------
__global__ __launch_bounds__(256) void fixup_kernel(const _Float16* __restrict__ p16,
                                                    const float* __restrict__ scal,
                                                    float* __restrict__ attn) {
  const long long n8 = 16777216LL;  // groups of 8 elements (2*16*2048*2048 / 8)
  const long long stride = (long long)gridDim.x * 256;
  for (long long i = (long long)blockIdx.x * 256 + threadIdx.x; i < n8; i += stride) {
    f16x8 p = reinterpret_cast<const f16x8*>(p16)[i];
    const float s = scal[i >> 8];   // 256 groups per 2048-wide row
    float4 lo = make_float4((float)p[0] * s, (float)p[1] * s,
                            (float)p[2] * s, (float)p[3] * s);
    float4 hi = make_float4((float)p[4] * s, (float)p[5] * s,
                            (float)p[6] * s, (float)p[7] * s);
    reinterpret_cast<float4*>(attn)[2 * i] = lo;
    reinterpret_cast<float4*>(attn)[2 * i + 1] = hi;
  }
}

// ---------------- host ----------------
extern "C" void kernel_launch(void* const* d_in, const int* in_sizes, int n_in,
                              void* d_out, int out_size, void* d_ws, size_t ws_size,
                              hipStream_t stream) {
  const float* q = (const float*)d_in[0];
  const float* k = (const float*)d_in[1];
  const float* v = (const float*)d_in[2];
  const float* mask = (const float*)d_in[3];
  const float* wq_w = (const float*)d_in[4];
  const float* wq_b = (const float*)d_in[5];
  const float* wk_w = (const float*)d_in[6];
  const float* wk_b = (const float*)d_in[7];
  const float* wv_w = (const float*)d_in[8];
  const float* wv_b = (const float*)d_in[9];
  const float* dw = (const float*)d_in[10];
  const float* db = (const float*)d_in[11];
  const float* rel = (const float*)d_in[12];

  char* ws = (char*)d_ws;
  _Float16* qhf  = (_Float16*)(ws + 0);
  _Float16* khf  = (_Float16*)(ws + 8388608);
  _Float16* vhT  = (_Float16*)(ws + 16777216);
  _Float16* o_h  = (_Float16*)(ws + 25165824);
  float* scal    = (float*)(ws + 33554432);
  unsigned short* mperm = (unsigned short*)(ws + 33816576);
  _Float16* p16  = (_Float16*)(ws + 50593792);   // 268 MB unnormalized p'

  float* out = (float*)d_out;
  float* attn_out = out + 4194304;

  prep_mask_perm<<<2048, 256, 0, stream>>>(mask, mperm);

  proj_gemm_kernel<<<768, 256, 0, stream>>>(q, k, v, wq_w, wk_w, wv_w,
                                            wq_b, wk_b, wv_b, qhf, khf, vhT);

  attn_pv_kernel<<<1024, 256, 0, stream>>>(qhf, khf, vhT, rel, mperm, o_h, p16, scal);

  fixup_kernel<<<4096, 256, 0, stream>>>(p16, scal, attn_out);

  dense_gemm_kernel<<<256, 256, 0, stream>>>(o_h, dw, db, out);
}